// Round 5
// baseline (281.001 us; speedup 1.0000x reference)
//
#include <hip/hip_runtime.h>
#include <math.h>

#define BATCH 16384
#define INFEAT 256
#define HID 128
#define NQ 10
#define NL 4
#define GSTRIDE 48   // floats per gate in gtab

typedef float v2f __attribute__((ext_vector_type(2)));

// ---------- cross-lane xor helper: DPP for 1,2,3,8; ds_swizzle for 4..31; shfl for 32+ ----------
template<int M>
__device__ __forceinline__ float lxor(float x) {
    if constexpr (M == 0) {
        return x;
    } else if constexpr (M < 4) {
        constexpr int ctrl = (0 ^ M) | ((1 ^ M) << 2) | ((2 ^ M) << 4) | ((3 ^ M) << 6);
        return __int_as_float(__builtin_amdgcn_update_dpp(
            __float_as_int(x), __float_as_int(x), ctrl, 0xF, 0xF, false));
    } else if constexpr (M == 8) {
        return __int_as_float(__builtin_amdgcn_update_dpp(
            __float_as_int(x), __float_as_int(x), 0x128, 0xF, 0xF, false));  // ROW_ROR:8 == xor8
    } else if constexpr (M < 32) {
        return __int_as_float(__builtin_amdgcn_ds_swizzle(
            __float_as_int(x), (M << 10) | 0x1F));
    } else {
        return __shfl_xor(x, M, 64);
    }
}

// full 64-lane sum, pure-VALU DPP chain (row_shr 1/2/4/8 + row_bcast 15/31),
// result broadcast via readlane(63).
__device__ __forceinline__ float dpp_sum(float v) {
    v += __int_as_float(__builtin_amdgcn_update_dpp(0, __float_as_int(v), 0x111, 0xF, 0xF, true));
    v += __int_as_float(__builtin_amdgcn_update_dpp(0, __float_as_int(v), 0x112, 0xF, 0xF, true));
    v += __int_as_float(__builtin_amdgcn_update_dpp(0, __float_as_int(v), 0x114, 0xF, 0xF, true));
    v += __int_as_float(__builtin_amdgcn_update_dpp(0, __float_as_int(v), 0x118, 0xF, 0xF, true));
    v += __int_as_float(__builtin_amdgcn_update_dpp(0, __float_as_int(v), 0x142, 0xF, 0xF, true));
    v += __int_as_float(__builtin_amdgcn_update_dpp(0, __float_as_int(v), 0x143, 0xF, 0xF, true));
    return __int_as_float(__builtin_amdgcn_readlane(__float_as_int(v), 63));
}

// gfx950 VALU cross-lane exchange; a and b MUST be distinct SSA values.
template<int HALF>
__device__ __forceinline__ void swap_pl(float& a, float& b) {
    if constexpr (HALF == 32)
        asm("v_permlane32_swap_b32 %0, %1" : "+v"(a), "+v"(b));
    else
        asm("v_permlane16_swap_b32 %0, %1" : "+v"(a), "+v"(b));
}

// ---------- explicit VOP3P packed-f32 helpers ----------
__device__ __forceinline__ v2f pks_mul(v2f c, v2f a) {
    v2f d; asm("v_pk_mul_f32 %0, %1, %2" : "=v"(d) : "s"(c), "v"(a)); return d;
}
__device__ __forceinline__ v2f pks_fma(v2f c, v2f a, v2f b) {
    v2f d; asm("v_pk_fma_f32 %0, %1, %2, %3" : "=v"(d) : "s"(c), "v"(a), "v"(b)); return d;
}
// src1 halves SWAPPED via op_sel
__device__ __forceinline__ v2f pks_fma_swap(v2f c, v2f a, v2f b) {
    v2f d; asm("v_pk_fma_f32 %0, %1, %2, %3 op_sel:[0,1,0] op_sel_hi:[1,0,1]"
               : "=v"(d) : "s"(c), "v"(a), "v"(b)); return d;
}
// src0 (SGPR pair) broadcast LOW half:  d = splat(c.x)*a + b
__device__ __forceinline__ v2f pks_fma_clo(v2f c, v2f a, v2f b) {
    v2f d; asm("v_pk_fma_f32 %0, %1, %2, %3 op_sel:[0,0,0] op_sel_hi:[0,1,1]"
               : "=v"(d) : "s"(c), "v"(a), "v"(b)); return d;
}
// src0 (SGPR pair) broadcast HIGH half: d = splat(c.y)*a + b
__device__ __forceinline__ v2f pks_fma_chi(v2f c, v2f a, v2f b) {
    v2f d; asm("v_pk_fma_f32 %0, %1, %2, %3 op_sel:[1,0,0] op_sel_hi:[1,1,1]"
               : "=v"(d) : "s"(c), "v"(a), "v"(b)); return d;
}
// v-coefficient with LOW-half broadcast
__device__ __forceinline__ v2f pkv_mul_c(v2f c, v2f a) {
    v2f d; asm("v_pk_mul_f32 %0, %1, %2 op_sel:[0,0] op_sel_hi:[0,1]"
               : "=v"(d) : "v"(c), "v"(a)); return d;
}
__device__ __forceinline__ v2f pkv_fma_c(v2f c, v2f a, v2f b) {
    v2f d; asm("v_pk_fma_f32 %0, %1, %2, %3 op_sel:[0,0,0] op_sel_hi:[0,1,1]"
               : "=v"(d) : "v"(c), "v"(a), "v"(b)); return d;
}

// ---- state: v2f AR[8], AI[8]; element e = 2k+h; qubit w(0..3) <-> e-bit(3-w);
// ---- qubits 4..9 <-> lane bits 5..0.  basis n = (e<<6)|lane
__device__ __forceinline__ float getv(const v2f (&A)[8], int e) {
    return (e & 1) ? A[e >> 1].y : A[e >> 1].x;
}
__device__ __forceinline__ void setv(v2f (&A)[8], int e, float v) {
    if (e & 1) A[e >> 1].y = v; else A[e >> 1].x = v;
}

// ================= RZ-factorized layer machinery =================
template<int KM>
__device__ __forceinline__ void reg_ry(const float* __restrict__ g,
                                       v2f (&AR)[8], v2f (&AI)[8]) {
    const v2f* __restrict__ gp = (const v2f*)g;
    const v2f C = gp[6], S = gp[7], Sn = gp[8];   // (c,c) (s,s) (-s,-s)
#pragma unroll
    for (int k0 = 0; k0 < 8; ++k0) {
        if (k0 & KM) continue;
        const int k1 = k0 | KM;
        v2f A0 = AR[k0], A1 = AR[k1], I0 = AI[k0], I1 = AI[k1];
        AR[k0] = pks_fma(Sn, A1, pks_mul(C, A0));   // c*a0 - s*a1
        AI[k0] = pks_fma(Sn, I1, pks_mul(C, I0));
        AR[k1] = pks_fma(C, A1, pks_mul(S, A0));    // s*a0 + c*a1
        AI[k1] = pks_fma(C, I1, pks_mul(S, I0));
    }
}

__device__ __forceinline__ void q3_ry(const float* __restrict__ g,
                                      v2f (&AR)[8], v2f (&AI)[8]) {
    const v2f* __restrict__ gp = (const v2f*)g;
    const v2f C = gp[9], Ssw = gp[10];   // (c,c), (-s, s)
#pragma unroll
    for (int k = 0; k < 8; ++k) {
        AR[k] = pks_fma_swap(Ssw, AR[k], pks_mul(C, AR[k]));
        AI[k] = pks_fma_swap(Ssw, AI[k], pks_mul(C, AI[k]));
    }
}

template<int HALF>
__device__ __forceinline__ void pl_ry(const float* __restrict__ g,
                                      v2f (&AR)[8], v2f (&AI)[8]) {
    const v2f* __restrict__ gp = (const v2f*)g;
    const v2f C = gp[6], S = gp[7], Sn = gp[8];
#pragma unroll
    for (int k0 = 0; k0 < 8; k0 += 2) {
        const int k1 = k0 + 1;
        float Xr0 = AR[k0].x, Xr1 = AR[k0].y, Yr0 = AR[k1].x, Yr1 = AR[k1].y;
        float Xi0 = AI[k0].x, Xi1 = AI[k0].y, Yi0 = AI[k1].x, Yi1 = AI[k1].y;
        swap_pl<HALF>(Xr0, Yr0); swap_pl<HALF>(Xr1, Yr1);
        swap_pl<HALF>(Xi0, Yi0); swap_pl<HALF>(Xi1, Yi1);
        v2f Xr; Xr.x = Xr0; Xr.y = Xr1;  v2f Yr; Yr.x = Yr0; Yr.y = Yr1;
        v2f Xi; Xi.x = Xi0; Xi.y = Xi1;  v2f Yi; Yi.x = Yi0; Yi.y = Yi1;
        v2f Pr = pks_fma(Sn, Yr, pks_mul(C, Xr));   // c*X - s*Y
        v2f Pi = pks_fma(Sn, Yi, pks_mul(C, Xi));
        v2f Qr = pks_fma(C, Yr, pks_mul(S, Xr));    // s*X + c*Y
        v2f Qi = pks_fma(C, Yi, pks_mul(S, Xi));
        float pr0 = Pr.x, pr1 = Pr.y, qr0 = Qr.x, qr1 = Qr.y;
        float pi0 = Pi.x, pi1 = Pi.y, qi0 = Qi.x, qi1 = Qi.y;
        swap_pl<HALF>(pr0, qr0); swap_pl<HALF>(pr1, qr1);
        swap_pl<HALF>(pi0, qi0); swap_pl<HALF>(pi1, qi1);
        AR[k0].x = pr0; AR[k0].y = pr1; AR[k1].x = qr0; AR[k1].y = qr1;
        AI[k0].x = pi0; AI[k0].y = pi1; AI[k1].x = qi0; AI[k1].y = qi1;
    }
}

template<int LB>
__device__ __forceinline__ void lane_ry(const float* __restrict__ g, int lane,
                                        v2f (&AR)[8], v2f (&AI)[8]) {
    const bool side = (lane >> LB) & 1;
    v2f Cm, Cp;
    Cm.x = g[8];                       // c (both sides)
    Cp.x = side ? g[10] : g[9];        // +s : -s
#pragma unroll
    for (int k = 0; k < 8; ++k) {
        v2f PR, PI;
        PR.x = lxor<(1 << LB)>(AR[k].x); PR.y = lxor<(1 << LB)>(AR[k].y);
        PI.x = lxor<(1 << LB)>(AI[k].x); PI.y = lxor<(1 << LB)>(AI[k].y);
        AR[k] = pkv_fma_c(Cp, PR, pkv_mul_c(Cm, AR[k]));
        AI[k] = pkv_fma_c(Cp, PI, pkv_mul_c(Cm, AI[k]));
    }
}

// merged RZ-diagonal pass
__device__ __forceinline__ void apply_diag(const float* __restrict__ dt, int lane,
                                           v2f (&AR)[8], v2f (&AI)[8]) {
    const float4* __restrict__ d4 = (const float4*)dt;
#pragma unroll
    for (int k = 0; k < 8; ++k) {
        float4 q = d4[k * 64 + lane];
        v2f CR; CR.x = q.x; CR.y = q.y;
        v2f CI; CI.x = q.z; CI.y = q.w;
        v2f ar = AR[k], ai = AI[k];
        v2f nR = __builtin_elementwise_fma(CI, -ai, CR * ar);
        v2f nI = __builtin_elementwise_fma(CI, ar, CR * ai);
        AR[k] = nR; AI[k] = nI;
    }
}

// ---- compile-time CNOT-ring tables (element index e, 4 bits) ----
constexpr int rr_src(int rs, int e) {
    int s = e;
    for (int i = 3 - rs; i >= 0; --i) s ^= ((s >> (3 - i)) & 1) << (3 - i - rs);
    return s;
}
constexpr int rl_mask(int rs, int e) {
    int m = 0;
    for (int i = (4 - rs < 0 ? 0 : 4 - rs); i <= 3; ++i)
        if ((e >> (3 - i)) & 1) m |= 1 << (9 - i - rs);
    return m;
}

template<int L>
__device__ __forceinline__ void do_gates_ry(const float* __restrict__ gt, int lane,
                                            v2f (&AR)[8], v2f (&AI)[8]) {
    const float* __restrict__ gb = gt + L * NQ * GSTRIDE;
    reg_ry<4>(gb + 0 * GSTRIDE, AR, AI);   // qubit0: e-mask 8
    reg_ry<2>(gb + 1 * GSTRIDE, AR, AI);   // qubit1: e-mask 4
    reg_ry<1>(gb + 2 * GSTRIDE, AR, AI);   // qubit2: e-mask 2
    q3_ry(gb + 3 * GSTRIDE, AR, AI);       // qubit3: e-mask 1
    pl_ry<32>(gb + 4 * GSTRIDE, AR, AI);
    pl_ry<16>(gb + 5 * GSTRIDE, AR, AI);
    lane_ry<3>(gb + 6 * GSTRIDE, lane, AR, AI);
    lane_ry<2>(gb + 7 * GSTRIDE, lane, AR, AI);
    lane_ry<1>(gb + 8 * GSTRIDE, lane, AR, AI);
    lane_ry<0>(gb + 9 * GSTRIDE, lane, AR, AI);
}

// CNOT-ring movement for layer L (only L=0..2 used; L=3 folded into measurement)
template<int L>
__device__ __forceinline__ void do_move(int lane, v2f (&AR)[8], v2f (&AI)[8]) {
    constexpr int rs = L + 1;
    int y = lane;
#pragma unroll
    for (int i = 9 - rs; i >= 4; --i)
        y ^= ((y >> (9 - i)) & 1) << (9 - i - rs);
    const int base = y << 2;
    {
        float nr[16], ni[16];
#pragma unroll
        for (int e = 0; e < 16; ++e) {
            const int src = rr_src(rs, e);
            const int am  = rl_mask(rs, e) << 2;
            nr[e] = __int_as_float(__builtin_amdgcn_ds_bpermute(base ^ am, __float_as_int(getv(AR, src))));
            ni[e] = __int_as_float(__builtin_amdgcn_ds_bpermute(base ^ am, __float_as_int(getv(AI, src))));
        }
#pragma unroll
        for (int k = 0; k < 8; ++k) {
            AR[k].x = nr[2 * k]; AR[k].y = nr[2 * k + 1];
            AI[k].x = ni[2 * k]; AI[k].y = ni[2 * k + 1];
        }
    }
    // LR: predicated element-pair swaps
#pragma unroll
    for (int i = 10 - rs; i <= 9; ++i) {
        const bool p = (lane >> (9 - i)) & 1;
        const int tm = 1 << (13 - i - rs);
#pragma unroll
        for (int e = 0; e < 16; ++e) {
            if (!(e & tm)) {
                const int e1 = e | tm;
                float v0r = getv(AR, e), v1r = getv(AR, e1);
                setv(AR, e, p ? v1r : v0r); setv(AR, e1, p ? v0r : v1r);
                float v0i = getv(AI, e), v1i = getv(AI, e1);
                setv(AI, e, p ? v1i : v0i); setv(AI, e1, p ? v0i : v1i);
            }
        }
    }
}

__device__ __forceinline__ float ftanh(float s) {
    float e = __expf(2.f * s);
    return 1.f - 2.f / (e + 1.f);
}

// ---------------- prep ----------------
__global__ void prep_kernel(const float* __restrict__ qw, const float* __restrict__ W1,
                            float* __restrict__ gtab, float* __restrict__ w1q,
                            float* __restrict__ dtab) {
    int tid = blockIdx.x * 256 + threadIdx.x;
    if (tid < 128 * 64) {
        int k2 = tid >> 6, l = tid & 63;
        float4 q;
        q.x = W1[(size_t)(2 * l)     * INFEAT + 2 * k2];
        q.y = W1[(size_t)(2 * l + 1) * INFEAT + 2 * k2];
        q.z = W1[(size_t)(2 * l)     * INFEAT + 2 * k2 + 1];
        q.w = W1[(size_t)(2 * l + 1) * INFEAT + 2 * k2 + 1];
        ((float4*)w1q)[tid] = q;
    }
    if (blockIdx.x == 0 && threadIdx.x < NL * NQ) {
        int t = threadIdx.x;
        float phi = qw[t * 3 + 0], th = qw[t * 3 + 1], om = qw[t * 3 + 2];
        float c = __cosf(th * 0.5f), s = __sinf(th * 0.5f);
        float a = 0.5f * (phi + om), b = 0.5f * (phi - om);
        float ca = __cosf(a), sa = __sinf(a);
        float cb = __cosf(b), sb = __sinf(b);
        float m00r = ca * c,  m00i = -sa * c;
        float m01r = -cb * s, m01i = -sb * s;
        float m10r = cb * s,  m10i = -sb * s;
        float m11r = ca * c,  m11i = sa * c;
        float* g = gtab + t * GSTRIDE;
        g[0] = m00r; g[1] = m00i; g[2] = m01r; g[3] = m01i;
        g[4] = m10r; g[5] = m10i; g[6] = m11r; g[7] = m11i;
        g[8] = c;  g[9] = -s;  g[10] = s;  g[11] = 0.f;
        g[12] = c;  g[13] = c;
        g[14] = s;  g[15] = s;
        g[16] = -s; g[17] = -s;
        g[18] = c;  g[19] = c;
        g[20] = -s; g[21] = s;
    }
    // merged RZ diagonals (fp64 phase accumulation)
    if (tid < 3 * 8 * 64) {
        const int ld = tid >> 9;
        const int k = (tid >> 6) & 7;
        const int lane = tid & 63;
        float cr[2], ci[2];
#pragma unroll
        for (int h = 0; h < 2; ++h) {
            const int n = ((2 * k + h) << 6) | lane;
            double a = 0.0;
            for (int w = 0; w < NQ; ++w) {
                const double bit = (double)((n >> (9 - w)) & 1) - 0.5;
                a += (double)qw[(ld + 1) * NQ * 3 + w * 3 + 0] * bit;
            }
            if (ld >= 1) {
                const int r = ld + 1;
                int m = n;
                for (int i = 9; i >= 0; --i) {
                    const int tq = (i + r) % 10;
                    m ^= ((m >> (9 - i)) & 1) << (9 - tq);
                }
                for (int w = 0; w < NQ; ++w) {
                    const double bit = (double)((m >> (9 - w)) & 1) - 0.5;
                    a += (double)qw[ld * NQ * 3 + w * 3 + 2] * bit;
                }
            }
            cr[h] = (float)cos(a);
            ci[h] = (float)sin(a);
        }
        float4 o;
        o.x = cr[0]; o.y = cr[1]; o.z = ci[0]; o.w = ci[1];
        ((float4*)dtab)[tid] = o;
    }
}

// ---------------- fused kernel: 1 wave / block, 2 rows / wave, ZERO LDS ----------------
// 8192 blocks x 64 thr; no barriers; no LDS.
// launch_bounds SESSION MAP (empirical): (256,4)->cap 64 (used 52, ok);
// (64,8)->cap 32 (SPILLED, 398MB scratch); unbounded->128 (occ 21%).
// => cap = 256/min_waves. (64,4) caps at 64 = the 8-waves/SIMD occupancy cliff.
// TRIPWIRE: WRITE_SIZE >> 1 MB means spills returned -> revert to unbounded.
__global__ __launch_bounds__(64, 4) void fused_kernel(
    const float* __restrict__ x, const float* __restrict__ w1q,
    const float* __restrict__ b1, const float* __restrict__ W2,
    const float* __restrict__ b2, const float* __restrict__ gtab,
    const float* __restrict__ dtab,
    const float* __restrict__ W3, const float* __restrict__ b3,
    const float* __restrict__ W4, const float* __restrict__ b4,
    float* __restrict__ out)
{
    const int lane = threadIdx.x;
    const int rowA = blockIdx.x * 2;

    // ---- MLP: h cols (2*lane, 2*lane+1) for BOTH rows; x rows wave-uniform -> s_load ----
    v2f accA = (v2f)(0.f), accB = (v2f)(0.f);
    const float4* __restrict__ xrA = (const float4*)(x + (size_t)rowA * INFEAT);
    const float4* __restrict__ xrB = (const float4*)(x + (size_t)(rowA + 1) * INFEAT);
    const float4* __restrict__ w1p = (const float4*)w1q + lane;
#pragma unroll 4
    for (int k4 = 0; k4 < 64; ++k4) {
        float4 xa = xrA[k4], xb = xrB[k4];                 // uniform
        float4 q0 = w1p[(2 * k4 + 0) * 64];
        float4 q1 = w1p[(2 * k4 + 1) * 64];
        v2f w0;  w0.x  = q0.x; w0.y  = q0.y;   // k = 4k4
        v2f w1v; w1v.x = q0.z; w1v.y = q0.w;   // k = 4k4+1
        v2f w2v; w2v.x = q1.x; w2v.y = q1.y;   // k = 4k4+2
        v2f w3v; w3v.x = q1.z; w3v.y = q1.w;   // k = 4k4+3
        v2f xa01; xa01.x = xa.x; xa01.y = xa.y;
        v2f xa23; xa23.x = xa.z; xa23.y = xa.w;
        v2f xb01; xb01.x = xb.x; xb01.y = xb.y;
        v2f xb23; xb23.x = xb.z; xb23.y = xb.w;
        accA = pks_fma_clo(xa01, w0,  accA);
        accA = pks_fma_chi(xa01, w1v, accA);
        accA = pks_fma_clo(xa23, w2v, accA);
        accA = pks_fma_chi(xa23, w3v, accA);
        accB = pks_fma_clo(xb01, w0,  accB);
        accB = pks_fma_chi(xb01, w1v, accB);
        accB = pks_fma_clo(xb23, w2v, accB);
        accB = pks_fma_chi(xb23, w3v, accB);
    }
    float2 b1v = ((const float2*)b1)[lane];
    const float hA0 = fmaxf(accA.x + b1v.x, 0.f);
    const float hA1 = fmaxf(accA.y + b1v.y, 0.f);
    const float hB0 = fmaxf(accB.x + b1v.x, 0.f);
    const float hB1 = fmaxf(accB.y + b1v.y, 0.f);

    // ---- per-row: angles -> circuit -> measurement -> head (loop NOT unrolled) ----
#pragma unroll 1
    for (int rr = 0; rr < 2; ++rr) {
        const float h0 = rr ? hB0 : hA0;
        const float h1 = rr ? hB1 : hA1;

        // angles = tanh(h@W2^T + b2), DPP-chain reductions
        float cth[NQ], sth[NQ];
#pragma unroll
        for (int w = 0; w < NQ; ++w) {
            float2 w2v = ((const float2*)(W2 + (size_t)w * HID))[lane];
            float aw = dpp_sum(fmaf(h0, w2v.x, h1 * w2v.y)) + b2[w];
            float th = ftanh(aw) * 0.5f;
            cth[w] = __cosf(th); sth[w] = __sinf(th);
        }

        // fused RY + layer-0 Rot product state
        float Lr, Li;
        {
            const float* __restrict__ g = gtab + 4 * GSTRIDE;
            bool bw = (lane >> 5) & 1;
            float g0 = bw ? g[4] : g[0], g1 = bw ? g[5] : g[1];
            float g2 = bw ? g[6] : g[2], g3 = bw ? g[7] : g[3];
            Lr = fmaf(g0, cth[4], g2 * sth[4]);
            Li = fmaf(g1, cth[4], g3 * sth[4]);
        }
#pragma unroll
        for (int w = 5; w < 10; ++w) {
            const float* __restrict__ g = gtab + w * GSTRIDE;
            bool bw = (lane >> (9 - w)) & 1;
            float g0 = bw ? g[4] : g[0], g1 = bw ? g[5] : g[1];
            float g2 = bw ? g[6] : g[2], g3 = bw ? g[7] : g[3];
            float fr = fmaf(g0, cth[w], g2 * sth[w]);
            float fi = fmaf(g1, cth[w], g3 * sth[w]);
            float nr = Lr * fr - Li * fi;
            float ni = Lr * fi + Li * fr;
            Lr = nr; Li = ni;
        }
        float q01r[4], q01i[4], q23r[4], q23i[4];
        {
            const float* __restrict__ ga = gtab + 0 * GSTRIDE;
            const float* __restrict__ gb = gtab + 1 * GSTRIDE;
            float a0r = fmaf(ga[0], cth[0], ga[2] * sth[0]);
            float a0i = fmaf(ga[1], cth[0], ga[3] * sth[0]);
            float b0r = fmaf(ga[4], cth[0], ga[6] * sth[0]);
            float b0i = fmaf(ga[5], cth[0], ga[7] * sth[0]);
            float a1r = fmaf(gb[0], cth[1], gb[2] * sth[1]);
            float a1i = fmaf(gb[1], cth[1], gb[3] * sth[1]);
            float b1r = fmaf(gb[4], cth[1], gb[6] * sth[1]);
            float b1i = fmaf(gb[5], cth[1], gb[7] * sth[1]);
#pragma unroll
            for (int j = 0; j < 4; ++j) {
                float f0r = (j & 2) ? b0r : a0r, f0i = (j & 2) ? b0i : a0i;
                float f1r = (j & 1) ? b1r : a1r, f1i = (j & 1) ? b1i : a1i;
                q01r[j] = f0r * f1r - f0i * f1i;
                q01i[j] = f0r * f1i + f0i * f1r;
            }
        }
        {
            const float* __restrict__ ga = gtab + 2 * GSTRIDE;
            const float* __restrict__ gb = gtab + 3 * GSTRIDE;
            float a2r = fmaf(ga[0], cth[2], ga[2] * sth[2]);
            float a2i = fmaf(ga[1], cth[2], ga[3] * sth[2]);
            float b2r = fmaf(ga[4], cth[2], ga[6] * sth[2]);
            float b2i = fmaf(ga[5], cth[2], ga[7] * sth[2]);
            float a3r = fmaf(gb[0], cth[3], gb[2] * sth[3]);
            float a3i = fmaf(gb[1], cth[3], gb[3] * sth[3]);
            float b3r = fmaf(gb[4], cth[3], gb[6] * sth[3]);
            float b3i = fmaf(gb[5], cth[3], gb[7] * sth[3]);
#pragma unroll
            for (int j = 0; j < 4; ++j) {
                float f2r = (j & 2) ? b2r : a2r, f2i = (j & 2) ? b2i : a2i;
                float f3r = (j & 1) ? b3r : a3r, f3i = (j & 1) ? b3i : a3i;
                q23r[j] = f2r * f3r - f2i * f3i;
                q23i[j] = f2r * f3i + f2i * f3r;
            }
        }
        v2f AR[8], AI[8];
#pragma unroll
        for (int e = 0; e < 16; ++e) {
            const int jh = e >> 2, jl = e & 3;
            float tr = q01r[jh] * q23r[jl] - q01i[jh] * q23i[jl];
            float ti = q01r[jh] * q23i[jl] + q01i[jh] * q23r[jl];
            float ar = tr * Lr - ti * Li;
            float ai = tr * Li + ti * Lr;
            setv(AR, e, ar); setv(AI, e, ai);
        }

        // circuit: moves 0..2 physical, move_3 folded into measurement
        do_move<0>(lane, AR, AI);
        apply_diag(dtab + 0 * 2048, lane, AR, AI);
        do_gates_ry<1>(gtab, lane, AR, AI);
        do_move<1>(lane, AR, AI);
        apply_diag(dtab + 1 * 2048, lane, AR, AI);
        do_gates_ry<2>(gtab, lane, AR, AI);
        do_move<2>(lane, AR, AI);
        apply_diag(dtab + 2 * 2048, lane, AR, AI);
        do_gates_ry<3>(gtab, lane, AR, AI);
        // (move_3: permutation before |amp|^2 -> masks below; omega-diag l3: dropped)

        // ---- Z expectations with P^-1-composed masks (r=4 ring) ----
        // w: 0:(10,8) 1:(5,4) 2:(10,34) 3:(5,17) 4:(8,32) 5:(4,16) 6:(2,8) 7:(1,4) 8:(8,34) 9:(4,17)
        v2f Pk[8];
#pragma unroll
        for (int k = 0; k < 8; ++k) Pk[k] = AR[k] * AR[k] + AI[k] * AI[k];
        v2f A0 = Pk[0] + Pk[1], B0 = Pk[2] + Pk[3], C0 = Pk[4] + Pk[5], D0 = Pk[6] + Pk[7];
        v2f a0 = Pk[0] - Pk[1], b0 = Pk[2] - Pk[3], c0 = Pk[4] - Pk[5], d0 = Pk[6] - Pk[7];
        v2f AB = A0 + B0, CD = C0 + D0;
        v2f S  = AB + CD;
        v2f W8 = AB - CD;
        v2f V  = (A0 - B0) + (C0 - D0);
        v2f E2 = a0 + b0, F2 = c0 + d0;
        v2f T2v = E2 + F2, U = E2 - F2;
        float t8  = W8.x + W8.y;           // re=8  (sign by e-bit3)
        float t4  = V.x + V.y;             // re=4
        float t5  = V.x - V.y;             // re=5
        float t2  = T2v.x + T2v.y;         // re=2
        float t10 = U.x + U.y;             // re=10
        float t1  = S.x - S.y;             // re=1
        const bool p4  = lane & 4;
        const bool p8  = lane & 8;
        const bool p16 = lane & 16;
        const bool p32 = lane & 32;
        const bool p34 = ((lane >> 5) ^ (lane >> 1)) & 1;
        const bool p17 = ((lane >> 4) ^ lane) & 1;
        float es[NQ];
        es[0] = dpp_sum(p8  ? -t10 : t10);
        es[1] = dpp_sum(p4  ? -t5  : t5);
        es[2] = dpp_sum(p34 ? -t10 : t10);
        es[3] = dpp_sum(p17 ? -t5  : t5);
        es[4] = dpp_sum(p32 ? -t8  : t8);
        es[5] = dpp_sum(p16 ? -t4  : t4);
        es[6] = dpp_sum(p8  ? -t2  : t2);
        es[7] = dpp_sum(p4  ? -t1  : t1);
        es[8] = dpp_sum(p34 ? -t8  : t8);
        es[9] = dpp_sum(p17 ? -t4  : t4);

        // ---- head: lane owns output cols (2*lane, 2*lane+1); W3 rows direct (L1-hot) ----
        const float4* __restrict__ w3r = (const float4*)(W3 + (size_t)lane * 2 * NQ);
        float4 wA = w3r[0], wB = w3r[1], wC = w3r[2], wD = w3r[3], wE = w3r[4];
        float2 b3v = ((const float2*)b3)[lane];
        float dd0 = b3v.x;
        dd0 = fmaf(wA.x, es[0], dd0); dd0 = fmaf(wA.y, es[1], dd0);
        dd0 = fmaf(wA.z, es[2], dd0); dd0 = fmaf(wA.w, es[3], dd0);
        dd0 = fmaf(wB.x, es[4], dd0); dd0 = fmaf(wB.y, es[5], dd0);
        dd0 = fmaf(wB.z, es[6], dd0); dd0 = fmaf(wB.w, es[7], dd0);
        dd0 = fmaf(wC.x, es[8], dd0); dd0 = fmaf(wC.y, es[9], dd0);
        float dd1 = b3v.y;
        dd1 = fmaf(wC.z, es[0], dd1); dd1 = fmaf(wC.w, es[1], dd1);
        dd1 = fmaf(wD.x, es[2], dd1); dd1 = fmaf(wD.y, es[3], dd1);
        dd1 = fmaf(wD.z, es[4], dd1); dd1 = fmaf(wD.w, es[5], dd1);
        dd1 = fmaf(wE.x, es[6], dd1); dd1 = fmaf(wE.y, es[7], dd1);
        dd1 = fmaf(wE.z, es[8], dd1); dd1 = fmaf(wE.w, es[9], dd1);
        dd0 = fmaxf(dd0, 0.f);
        dd1 = fmaxf(dd1, 0.f);
        float2 w4v = ((const float2*)W4)[lane];
        float accv = fmaf(dd0, w4v.x, dd1 * w4v.y);
        accv = dpp_sum(accv);
        if (lane == 0) out[rowA + rr] = accv + b4[0];
    }
}

extern "C" void kernel_launch(void* const* d_in, const int* in_sizes, int n_in,
                              void* d_out, int out_size, void* d_ws, size_t ws_size,
                              hipStream_t stream) {
    const float* x  = (const float*)d_in[0];
    const float* W1 = (const float*)d_in[1];
    const float* b1 = (const float*)d_in[2];
    const float* W2 = (const float*)d_in[3];
    const float* b2 = (const float*)d_in[4];
    const float* qw = (const float*)d_in[5];
    const float* W3 = (const float*)d_in[6];
    const float* b3 = (const float*)d_in[7];
    const float* W4 = (const float*)d_in[8];
    const float* b4 = (const float*)d_in[9];
    float* gtab = (float*)d_ws;                    // 40*48 = 1920 floats
    float* w1q  = (float*)d_ws + 2048;             // 32768 floats (pair-packed)
    float* dtab = (float*)d_ws + 2048 + 32768;     // 6144 floats (3 merged RZ diagonals)
    float* out  = (float*)d_out;

    prep_kernel<<<(128 * 64 + 255) / 256, 256, 0, stream>>>(qw, W1, gtab, w1q, dtab);
    fused_kernel<<<BATCH / 2, 64, 0, stream>>>(x, w1q, b1, W2, b2, gtab, dtab, W3, b3, W4, b4, out);
}

// Round 6
// 180.642 us; speedup vs baseline: 1.5556x; 1.5556x over previous
//
#include <hip/hip_runtime.h>
#include <math.h>

#define BATCH 16384
#define INFEAT 256
#define HID 128
#define NQ 10
#define NL 4
#define GSTRIDE 48   // floats per gate in gtab

typedef float v2f __attribute__((ext_vector_type(2)));

// ---------- cross-lane xor helper: DPP for 1,2,3,8; ds_swizzle for 4..31; shfl for 32+ ----------
template<int M>
__device__ __forceinline__ float lxor(float x) {
    if constexpr (M == 0) {
        return x;
    } else if constexpr (M < 4) {
        constexpr int ctrl = (0 ^ M) | ((1 ^ M) << 2) | ((2 ^ M) << 4) | ((3 ^ M) << 6);
        return __int_as_float(__builtin_amdgcn_update_dpp(
            __float_as_int(x), __float_as_int(x), ctrl, 0xF, 0xF, false));
    } else if constexpr (M == 8) {
        return __int_as_float(__builtin_amdgcn_update_dpp(
            __float_as_int(x), __float_as_int(x), 0x128, 0xF, 0xF, false));  // ROW_ROR:8 == xor8
    } else if constexpr (M < 32) {
        return __int_as_float(__builtin_amdgcn_ds_swizzle(
            __float_as_int(x), (M << 10) | 0x1F));
    } else {
        return __shfl_xor(x, M, 64);
    }
}

// full 64-lane sum, pure-VALU DPP chain, result broadcast via readlane(63).
__device__ __forceinline__ float dpp_sum(float v) {
    v += __int_as_float(__builtin_amdgcn_update_dpp(0, __float_as_int(v), 0x111, 0xF, 0xF, true));
    v += __int_as_float(__builtin_amdgcn_update_dpp(0, __float_as_int(v), 0x112, 0xF, 0xF, true));
    v += __int_as_float(__builtin_amdgcn_update_dpp(0, __float_as_int(v), 0x114, 0xF, 0xF, true));
    v += __int_as_float(__builtin_amdgcn_update_dpp(0, __float_as_int(v), 0x118, 0xF, 0xF, true));
    v += __int_as_float(__builtin_amdgcn_update_dpp(0, __float_as_int(v), 0x142, 0xF, 0xF, true));
    v += __int_as_float(__builtin_amdgcn_update_dpp(0, __float_as_int(v), 0x143, 0xF, 0xF, true));
    return __int_as_float(__builtin_amdgcn_readlane(__float_as_int(v), 63));
}

// gfx950 VALU cross-lane exchange; a and b MUST be distinct SSA values.
template<int HALF>
__device__ __forceinline__ void swap_pl(float& a, float& b) {
    if constexpr (HALF == 32)
        asm("v_permlane32_swap_b32 %0, %1" : "+v"(a), "+v"(b));
    else
        asm("v_permlane16_swap_b32 %0, %1" : "+v"(a), "+v"(b));
}

// ---------- explicit VOP3P packed-f32 helpers ----------
__device__ __forceinline__ v2f pks_mul(v2f c, v2f a) {
    v2f d; asm("v_pk_mul_f32 %0, %1, %2" : "=v"(d) : "s"(c), "v"(a)); return d;
}
__device__ __forceinline__ v2f pks_fma(v2f c, v2f a, v2f b) {
    v2f d; asm("v_pk_fma_f32 %0, %1, %2, %3" : "=v"(d) : "s"(c), "v"(a), "v"(b)); return d;
}
// src1 halves SWAPPED via op_sel
__device__ __forceinline__ v2f pks_fma_swap(v2f c, v2f a, v2f b) {
    v2f d; asm("v_pk_fma_f32 %0, %1, %2, %3 op_sel:[0,1,0] op_sel_hi:[1,0,1]"
               : "=v"(d) : "s"(c), "v"(a), "v"(b)); return d;
}
// v-coefficient with LOW-half broadcast
__device__ __forceinline__ v2f pkv_mul_c(v2f c, v2f a) {
    v2f d; asm("v_pk_mul_f32 %0, %1, %2 op_sel:[0,0] op_sel_hi:[0,1]"
               : "=v"(d) : "v"(c), "v"(a)); return d;
}
__device__ __forceinline__ v2f pkv_fma_c(v2f c, v2f a, v2f b) {
    v2f d; asm("v_pk_fma_f32 %0, %1, %2, %3 op_sel:[0,0,0] op_sel_hi:[0,1,1]"
               : "=v"(d) : "v"(c), "v"(a), "v"(b)); return d;
}

// ---- state: v2f AR[8], AI[8]; element e = 2k+h; qubit w(0..3) <-> e-bit(3-w);
// ---- qubits 4..9 <-> lane bits 5..0.  basis n = (e<<6)|lane
__device__ __forceinline__ float getv(const v2f (&A)[8], int e) {
    return (e & 1) ? A[e >> 1].y : A[e >> 1].x;
}
__device__ __forceinline__ void setv(v2f (&A)[8], int e, float v) {
    if (e & 1) A[e >> 1].y = v; else A[e >> 1].x = v;
}

// ================= RZ-factorized layer machinery =================
template<int KM>
__device__ __forceinline__ void reg_ry(const float* __restrict__ g,
                                       v2f (&AR)[8], v2f (&AI)[8]) {
    const v2f* __restrict__ gp = (const v2f*)g;
    const v2f C = gp[6], S = gp[7], Sn = gp[8];   // (c,c) (s,s) (-s,-s)
#pragma unroll
    for (int k0 = 0; k0 < 8; ++k0) {
        if (k0 & KM) continue;
        const int k1 = k0 | KM;
        v2f A0 = AR[k0], A1 = AR[k1], I0 = AI[k0], I1 = AI[k1];
        AR[k0] = pks_fma(Sn, A1, pks_mul(C, A0));   // c*a0 - s*a1
        AI[k0] = pks_fma(Sn, I1, pks_mul(C, I0));
        AR[k1] = pks_fma(C, A1, pks_mul(S, A0));    // s*a0 + c*a1
        AI[k1] = pks_fma(C, I1, pks_mul(S, I0));
    }
}

__device__ __forceinline__ void q3_ry(const float* __restrict__ g,
                                      v2f (&AR)[8], v2f (&AI)[8]) {
    const v2f* __restrict__ gp = (const v2f*)g;
    const v2f C = gp[9], Ssw = gp[10];   // (c,c), (-s, s)
#pragma unroll
    for (int k = 0; k < 8; ++k) {
        AR[k] = pks_fma_swap(Ssw, AR[k], pks_mul(C, AR[k]));
        AI[k] = pks_fma_swap(Ssw, AI[k], pks_mul(C, AI[k]));
    }
}

template<int HALF>
__device__ __forceinline__ void pl_ry(const float* __restrict__ g,
                                      v2f (&AR)[8], v2f (&AI)[8]) {
    const v2f* __restrict__ gp = (const v2f*)g;
    const v2f C = gp[6], S = gp[7], Sn = gp[8];
#pragma unroll
    for (int k0 = 0; k0 < 8; k0 += 2) {
        const int k1 = k0 + 1;
        float Xr0 = AR[k0].x, Xr1 = AR[k0].y, Yr0 = AR[k1].x, Yr1 = AR[k1].y;
        float Xi0 = AI[k0].x, Xi1 = AI[k0].y, Yi0 = AI[k1].x, Yi1 = AI[k1].y;
        swap_pl<HALF>(Xr0, Yr0); swap_pl<HALF>(Xr1, Yr1);
        swap_pl<HALF>(Xi0, Yi0); swap_pl<HALF>(Xi1, Yi1);
        v2f Xr; Xr.x = Xr0; Xr.y = Xr1;  v2f Yr; Yr.x = Yr0; Yr.y = Yr1;
        v2f Xi; Xi.x = Xi0; Xi.y = Xi1;  v2f Yi; Yi.x = Yi0; Yi.y = Yi1;
        v2f Pr = pks_fma(Sn, Yr, pks_mul(C, Xr));   // c*X - s*Y
        v2f Pi = pks_fma(Sn, Yi, pks_mul(C, Xi));
        v2f Qr = pks_fma(C, Yr, pks_mul(S, Xr));    // s*X + c*Y
        v2f Qi = pks_fma(C, Yi, pks_mul(S, Xi));
        float pr0 = Pr.x, pr1 = Pr.y, qr0 = Qr.x, qr1 = Qr.y;
        float pi0 = Pi.x, pi1 = Pi.y, qi0 = Qi.x, qi1 = Qi.y;
        swap_pl<HALF>(pr0, qr0); swap_pl<HALF>(pr1, qr1);
        swap_pl<HALF>(pi0, qi0); swap_pl<HALF>(pi1, qi1);
        AR[k0].x = pr0; AR[k0].y = pr1; AR[k1].x = qr0; AR[k1].y = qr1;
        AI[k0].x = pi0; AI[k0].y = pi1; AI[k1].x = qi0; AI[k1].y = qi1;
    }
}

template<int LB>
__device__ __forceinline__ void lane_ry(const float* __restrict__ g, int lane,
                                        v2f (&AR)[8], v2f (&AI)[8]) {
    const bool side = (lane >> LB) & 1;
    v2f Cm, Cp;
    Cm.x = g[8];                       // c (both sides)
    Cp.x = side ? g[10] : g[9];        // +s : -s
#pragma unroll
    for (int k = 0; k < 8; ++k) {
        v2f PR, PI;
        PR.x = lxor<(1 << LB)>(AR[k].x); PR.y = lxor<(1 << LB)>(AR[k].y);
        PI.x = lxor<(1 << LB)>(AI[k].x); PI.y = lxor<(1 << LB)>(AI[k].y);
        AR[k] = pkv_fma_c(Cp, PR, pkv_mul_c(Cm, AR[k]));
        AI[k] = pkv_fma_c(Cp, PI, pkv_mul_c(Cm, AI[k]));
    }
}

// merged RZ-diagonal pass
__device__ __forceinline__ void apply_diag(const float* __restrict__ dt, int lane,
                                           v2f (&AR)[8], v2f (&AI)[8]) {
    const float4* __restrict__ d4 = (const float4*)dt;
#pragma unroll
    for (int k = 0; k < 8; ++k) {
        float4 q = d4[k * 64 + lane];
        v2f CR; CR.x = q.x; CR.y = q.y;
        v2f CI; CI.x = q.z; CI.y = q.w;
        v2f ar = AR[k], ai = AI[k];
        v2f nR = __builtin_elementwise_fma(CI, -ai, CR * ar);
        v2f nI = __builtin_elementwise_fma(CI, ar, CR * ai);
        AR[k] = nR; AI[k] = nI;
    }
}

// ---- compile-time CNOT-ring tables (element index e, 4 bits) ----
constexpr int rr_src(int rs, int e) {
    int s = e;
    for (int i = 3 - rs; i >= 0; --i) s ^= ((s >> (3 - i)) & 1) << (3 - i - rs);
    return s;
}
constexpr int rl_mask(int rs, int e) {
    int m = 0;
    for (int i = (4 - rs < 0 ? 0 : 4 - rs); i <= 3; ++i)
        if ((e >> (3 - i)) & 1) m |= 1 << (9 - i - rs);
    return m;
}

template<int L>
__device__ __forceinline__ void do_gates_ry(const float* __restrict__ gt, int lane,
                                            v2f (&AR)[8], v2f (&AI)[8]) {
    const float* __restrict__ gb = gt + L * NQ * GSTRIDE;
    reg_ry<4>(gb + 0 * GSTRIDE, AR, AI);   // qubit0: e-mask 8
    reg_ry<2>(gb + 1 * GSTRIDE, AR, AI);   // qubit1: e-mask 4
    reg_ry<1>(gb + 2 * GSTRIDE, AR, AI);   // qubit2: e-mask 2
    q3_ry(gb + 3 * GSTRIDE, AR, AI);       // qubit3: e-mask 1
    pl_ry<32>(gb + 4 * GSTRIDE, AR, AI);
    pl_ry<16>(gb + 5 * GSTRIDE, AR, AI);
    lane_ry<3>(gb + 6 * GSTRIDE, lane, AR, AI);
    lane_ry<2>(gb + 7 * GSTRIDE, lane, AR, AI);
    lane_ry<1>(gb + 8 * GSTRIDE, lane, AR, AI);
    lane_ry<0>(gb + 9 * GSTRIDE, lane, AR, AI);
}

// CNOT-ring movement for layer L (only L=0..2 used; L=3 folded into measurement)
template<int L>
__device__ __forceinline__ void do_move(int lane, v2f (&AR)[8], v2f (&AI)[8]) {
    constexpr int rs = L + 1;
    int y = lane;
#pragma unroll
    for (int i = 9 - rs; i >= 4; --i)
        y ^= ((y >> (9 - i)) & 1) << (9 - i - rs);
    const int base = y << 2;
    {
        float nr[16], ni[16];
#pragma unroll
        for (int e = 0; e < 16; ++e) {
            const int src = rr_src(rs, e);
            const int am  = rl_mask(rs, e) << 2;
            nr[e] = __int_as_float(__builtin_amdgcn_ds_bpermute(base ^ am, __float_as_int(getv(AR, src))));
            ni[e] = __int_as_float(__builtin_amdgcn_ds_bpermute(base ^ am, __float_as_int(getv(AI, src))));
        }
#pragma unroll
        for (int k = 0; k < 8; ++k) {
            AR[k].x = nr[2 * k]; AR[k].y = nr[2 * k + 1];
            AI[k].x = ni[2 * k]; AI[k].y = ni[2 * k + 1];
        }
    }
    // LR: predicated element-pair swaps
#pragma unroll
    for (int i = 10 - rs; i <= 9; ++i) {
        const bool p = (lane >> (9 - i)) & 1;
        const int tm = 1 << (13 - i - rs);
#pragma unroll
        for (int e = 0; e < 16; ++e) {
            if (!(e & tm)) {
                const int e1 = e | tm;
                float v0r = getv(AR, e), v1r = getv(AR, e1);
                setv(AR, e, p ? v1r : v0r); setv(AR, e1, p ? v0r : v1r);
                float v0i = getv(AI, e), v1i = getv(AI, e1);
                setv(AI, e, p ? v1i : v0i); setv(AI, e1, p ? v0i : v1i);
            }
        }
    }
}

__device__ __forceinline__ float ftanh(float s) {
    float e = __expf(2.f * s);
    return 1.f - 2.f / (e + 1.f);
}

// ---------------- prep ----------------
__global__ void prep_kernel(const float* __restrict__ qw, const float* __restrict__ W1,
                            float* __restrict__ gtab, float* __restrict__ w1q,
                            float* __restrict__ dtab) {
    int tid = blockIdx.x * 256 + threadIdx.x;
    if (tid < 128 * 64) {
        int k2 = tid >> 6, l = tid & 63;
        float4 q;
        q.x = W1[(size_t)(2 * l)     * INFEAT + 2 * k2];
        q.y = W1[(size_t)(2 * l + 1) * INFEAT + 2 * k2];
        q.z = W1[(size_t)(2 * l)     * INFEAT + 2 * k2 + 1];
        q.w = W1[(size_t)(2 * l + 1) * INFEAT + 2 * k2 + 1];
        ((float4*)w1q)[tid] = q;
    }
    if (blockIdx.x == 0 && threadIdx.x < NL * NQ) {
        int t = threadIdx.x;
        float phi = qw[t * 3 + 0], th = qw[t * 3 + 1], om = qw[t * 3 + 2];
        float c = __cosf(th * 0.5f), s = __sinf(th * 0.5f);
        float a = 0.5f * (phi + om), b = 0.5f * (phi - om);
        float ca = __cosf(a), sa = __sinf(a);
        float cb = __cosf(b), sb = __sinf(b);
        float m00r = ca * c,  m00i = -sa * c;
        float m01r = -cb * s, m01i = -sb * s;
        float m10r = cb * s,  m10i = -sb * s;
        float m11r = ca * c,  m11i = sa * c;
        float* g = gtab + t * GSTRIDE;
        g[0] = m00r; g[1] = m00i; g[2] = m01r; g[3] = m01i;
        g[4] = m10r; g[5] = m10i; g[6] = m11r; g[7] = m11i;
        g[8] = c;  g[9] = -s;  g[10] = s;  g[11] = 0.f;
        g[12] = c;  g[13] = c;
        g[14] = s;  g[15] = s;
        g[16] = -s; g[17] = -s;
        g[18] = c;  g[19] = c;
        g[20] = -s; g[21] = s;
    }
    // merged RZ diagonals (fp64 phase accumulation)
    if (tid < 3 * 8 * 64) {
        const int ld = tid >> 9;
        const int k = (tid >> 6) & 7;
        const int lane = tid & 63;
        float cr[2], ci[2];
#pragma unroll
        for (int h = 0; h < 2; ++h) {
            const int n = ((2 * k + h) << 6) | lane;
            double a = 0.0;
            for (int w = 0; w < NQ; ++w) {
                const double bit = (double)((n >> (9 - w)) & 1) - 0.5;
                a += (double)qw[(ld + 1) * NQ * 3 + w * 3 + 0] * bit;
            }
            if (ld >= 1) {
                const int r = ld + 1;
                int m = n;
                for (int i = 9; i >= 0; --i) {
                    const int tq = (i + r) % 10;
                    m ^= ((m >> (9 - i)) & 1) << (9 - tq);
                }
                for (int w = 0; w < NQ; ++w) {
                    const double bit = (double)((m >> (9 - w)) & 1) - 0.5;
                    a += (double)qw[ld * NQ * 3 + w * 3 + 2] * bit;
                }
            }
            cr[h] = (float)cos(a);
            ci[h] = (float)sin(a);
        }
        float4 o;
        o.x = cr[0]; o.y = cr[1]; o.z = ci[0]; o.w = ci[1];
        ((float4*)dtab)[tid] = o;
    }
}

// ---------------- fused kernel: R1 4-wave chassis + move3-fold + mask measurement ----------------
// SESSION MAP: 4-wave/256-thr k-split MLP = only structure fitting <=64 VGPR unspilled
// (R1: 52 VGPR, 130us). 1-wave variants need 70-128 VGPR (R3 unbounded=128, R4 cap64=spill).
// (256,4) caps VGPR at 64 (proven R1). TRIPWIRE: WRITE_SIZE >> 1 MB = spills returned.
__global__ __launch_bounds__(256, 4) void fused_kernel(
    const float* __restrict__ x, const float* __restrict__ w1q,
    const float* __restrict__ b1, const float* __restrict__ W2,
    const float* __restrict__ b2, const float* __restrict__ gtab,
    const float* __restrict__ dtab,
    const float* __restrict__ W3, const float* __restrict__ b3,
    const float* __restrict__ W4, const float* __restrict__ b4,
    float* __restrict__ out)
{
    __shared__ v2f hpart[4][4][64];   // [k-slice wave][row][lane(2 cols)]

    const int t = threadIdx.x;
    const int lane = t & 63;
    const int wid = t >> 6;
    const int row0 = blockIdx.x * 4;
    const int ukw = __builtin_amdgcn_readfirstlane(wid);

    // ---- MLP phase 1: partial h for all 4 rows over k-slice [64*ukw, 64*ukw+64) ----
    v2f acc[4];
#pragma unroll
    for (int r = 0; r < 4; ++r) acc[r] = (v2f)(0.f);
    const float4* __restrict__ xr0 = (const float4*)(x + (size_t)(row0 + 0) * INFEAT + ukw * 64);
    const float4* __restrict__ xr1 = (const float4*)(x + (size_t)(row0 + 1) * INFEAT + ukw * 64);
    const float4* __restrict__ xr2 = (const float4*)(x + (size_t)(row0 + 2) * INFEAT + ukw * 64);
    const float4* __restrict__ xr3 = (const float4*)(x + (size_t)(row0 + 3) * INFEAT + ukw * 64);
    const float4* __restrict__ w1p = (const float4*)w1q + (size_t)ukw * 32 * 64 + lane;
#pragma unroll 4
    for (int kk4 = 0; kk4 < 16; ++kk4) {
        float4 x0 = xr0[kk4], x1 = xr1[kk4], x2 = xr2[kk4], x3 = xr3[kk4];
        float xk[4][4] = {{x0.x, x0.y, x0.z, x0.w}, {x1.x, x1.y, x1.z, x1.w},
                          {x2.x, x2.y, x2.z, x2.w}, {x3.x, x3.y, x3.z, x3.w}};
        float4 q0 = w1p[(2 * kk4 + 0) * 64];
        float4 q1 = w1p[(2 * kk4 + 1) * 64];
        v2f w0; w0.x = q0.x; w0.y = q0.y;   // k = 4kk4
        v2f w1; w1.x = q0.z; w1.y = q0.w;   // k = 4kk4+1
        v2f w2; w2.x = q1.x; w2.y = q1.y;   // k = 4kk4+2
        v2f w3; w3.x = q1.z; w3.y = q1.w;   // k = 4kk4+3
#pragma unroll
        for (int r = 0; r < 4; ++r) {
            v2f xb;
            xb.x = xk[r][0]; xb.y = xk[r][0];
            acc[r] = __builtin_elementwise_fma(xb, w0, acc[r]);
            xb.x = xk[r][1]; xb.y = xk[r][1];
            acc[r] = __builtin_elementwise_fma(xb, w1, acc[r]);
            xb.x = xk[r][2]; xb.y = xk[r][2];
            acc[r] = __builtin_elementwise_fma(xb, w2, acc[r]);
            xb.x = xk[r][3]; xb.y = xk[r][3];
            acc[r] = __builtin_elementwise_fma(xb, w3, acc[r]);
        }
    }
#pragma unroll
    for (int r = 0; r < 4; ++r) hpart[wid][r][lane] = acc[r];
    __syncthreads();

    // ---- MLP phase 2 ----
    v2f hs = hpart[0][wid][lane];
    hs += hpart[1][wid][lane];
    hs += hpart[2][wid][lane];
    hs += hpart[3][wid][lane];
    float2 b1v = ((const float2*)b1)[lane];
    float h0 = fmaxf(hs.x + b1v.x, 0.f);
    float h1 = fmaxf(hs.y + b1v.y, 0.f);

    const int row = row0 + wid;

    // ---- angles = tanh(h@W2^T + b2), DPP-chain reductions (0 DS) ----
    float cth[NQ], sth[NQ];
#pragma unroll
    for (int w = 0; w < NQ; ++w) {
        float2 w2v = ((const float2*)(W2 + (size_t)w * HID))[lane];
        float aw = dpp_sum(fmaf(h0, w2v.x, h1 * w2v.y)) + b2[w];
        float th = ftanh(aw) * 0.5f;
        cth[w] = __cosf(th); sth[w] = __sinf(th);
    }

    // ---- fused RY + layer-0 Rot product state ----
    float Lr, Li;
    {
        const float* __restrict__ g = gtab + 4 * GSTRIDE;
        bool bw = (lane >> 5) & 1;
        float g0 = bw ? g[4] : g[0], g1 = bw ? g[5] : g[1];
        float g2 = bw ? g[6] : g[2], g3 = bw ? g[7] : g[3];
        Lr = fmaf(g0, cth[4], g2 * sth[4]);
        Li = fmaf(g1, cth[4], g3 * sth[4]);
    }
#pragma unroll
    for (int w = 5; w < 10; ++w) {
        const float* __restrict__ g = gtab + w * GSTRIDE;
        bool bw = (lane >> (9 - w)) & 1;
        float g0 = bw ? g[4] : g[0], g1 = bw ? g[5] : g[1];
        float g2 = bw ? g[6] : g[2], g3 = bw ? g[7] : g[3];
        float fr = fmaf(g0, cth[w], g2 * sth[w]);
        float fi = fmaf(g1, cth[w], g3 * sth[w]);
        float nr = Lr * fr - Li * fi;
        float ni = Lr * fi + Li * fr;
        Lr = nr; Li = ni;
    }
    float q01r[4], q01i[4], q23r[4], q23i[4];
    {
        const float* __restrict__ ga = gtab + 0 * GSTRIDE;
        const float* __restrict__ gb = gtab + 1 * GSTRIDE;
        float a0r = fmaf(ga[0], cth[0], ga[2] * sth[0]);
        float a0i = fmaf(ga[1], cth[0], ga[3] * sth[0]);
        float b0r = fmaf(ga[4], cth[0], ga[6] * sth[0]);
        float b0i = fmaf(ga[5], cth[0], ga[7] * sth[0]);
        float a1r = fmaf(gb[0], cth[1], gb[2] * sth[1]);
        float a1i = fmaf(gb[1], cth[1], gb[3] * sth[1]);
        float b1r = fmaf(gb[4], cth[1], gb[6] * sth[1]);
        float b1i = fmaf(gb[5], cth[1], gb[7] * sth[1]);
#pragma unroll
        for (int j = 0; j < 4; ++j) {
            float f0r = (j & 2) ? b0r : a0r, f0i = (j & 2) ? b0i : a0i;
            float f1r = (j & 1) ? b1r : a1r, f1i = (j & 1) ? b1i : a1i;
            q01r[j] = f0r * f1r - f0i * f1i;
            q01i[j] = f0r * f1i + f0i * f1r;
        }
    }
    {
        const float* __restrict__ ga = gtab + 2 * GSTRIDE;
        const float* __restrict__ gb = gtab + 3 * GSTRIDE;
        float a2r = fmaf(ga[0], cth[2], ga[2] * sth[2]);
        float a2i = fmaf(ga[1], cth[2], ga[3] * sth[2]);
        float b2r = fmaf(ga[4], cth[2], ga[6] * sth[2]);
        float b2i = fmaf(ga[5], cth[2], ga[7] * sth[2]);
        float a3r = fmaf(gb[0], cth[3], gb[2] * sth[3]);
        float a3i = fmaf(gb[1], cth[3], gb[3] * sth[3]);
        float b3r = fmaf(gb[4], cth[3], gb[6] * sth[3]);
        float b3i = fmaf(gb[5], cth[3], gb[7] * sth[3]);
#pragma unroll
        for (int j = 0; j < 4; ++j) {
            float f2r = (j & 2) ? b2r : a2r, f2i = (j & 2) ? b2i : a2i;
            float f3r = (j & 1) ? b3r : a3r, f3i = (j & 1) ? b3i : a3i;
            q23r[j] = f2r * f3r - f2i * f3i;
            q23i[j] = f2r * f3i + f2i * f3r;
        }
    }
    v2f AR[8], AI[8];
#pragma unroll
    for (int e = 0; e < 16; ++e) {
        const int jh = e >> 2, jl = e & 3;
        float tr = q01r[jh] * q23r[jl] - q01i[jh] * q23i[jl];
        float ti = q01r[jh] * q23i[jl] + q01i[jh] * q23r[jl];
        float ar = tr * Lr - ti * Li;
        float ai = tr * Li + ti * Lr;
        setv(AR, e, ar); setv(AI, e, ai);
    }

    // ---- circuit: moves 0..2 physical, move_3 folded into measurement ----
    do_move<0>(lane, AR, AI);
    apply_diag(dtab + 0 * 2048, lane, AR, AI);
    do_gates_ry<1>(gtab, lane, AR, AI);
    do_move<1>(lane, AR, AI);
    apply_diag(dtab + 1 * 2048, lane, AR, AI);
    do_gates_ry<2>(gtab, lane, AR, AI);
    do_move<2>(lane, AR, AI);
    apply_diag(dtab + 2 * 2048, lane, AR, AI);
    do_gates_ry<3>(gtab, lane, AR, AI);
    // (move_3: permutation before |amp|^2 -> masks below; omega-diag l3: dropped)

    // ---- Z expectations with P^-1-composed masks (r=4 ring) ----
    // w: 0:(10,8) 1:(5,4) 2:(10,34) 3:(5,17) 4:(8,32) 5:(4,16) 6:(2,8) 7:(1,4) 8:(8,34) 9:(4,17)
    v2f Pk[8];
#pragma unroll
    for (int k = 0; k < 8; ++k) Pk[k] = AR[k] * AR[k] + AI[k] * AI[k];
    v2f A0 = Pk[0] + Pk[1], B0 = Pk[2] + Pk[3], C0 = Pk[4] + Pk[5], D0 = Pk[6] + Pk[7];
    v2f a0 = Pk[0] - Pk[1], b0 = Pk[2] - Pk[3], c0 = Pk[4] - Pk[5], d0 = Pk[6] - Pk[7];
    v2f AB = A0 + B0, CD = C0 + D0;
    v2f S  = AB + CD;
    v2f W8 = AB - CD;
    v2f V  = (A0 - B0) + (C0 - D0);
    v2f E2 = a0 + b0, F2 = c0 + d0;
    v2f T2v = E2 + F2, U = E2 - F2;
    float t8  = W8.x + W8.y;           // re=8  (sign by e-bit3)
    float t4  = V.x + V.y;             // re=4
    float t5  = V.x - V.y;             // re=5
    float t2  = T2v.x + T2v.y;         // re=2
    float t10 = U.x + U.y;             // re=10
    float t1  = S.x - S.y;             // re=1
    const bool p4  = lane & 4;
    const bool p8  = lane & 8;
    const bool p16 = lane & 16;
    const bool p32 = lane & 32;
    const bool p34 = ((lane >> 5) ^ (lane >> 1)) & 1;
    const bool p17 = ((lane >> 4) ^ lane) & 1;
    float es[NQ];
    es[0] = dpp_sum(p8  ? -t10 : t10);
    es[1] = dpp_sum(p4  ? -t5  : t5);
    es[2] = dpp_sum(p34 ? -t10 : t10);
    es[3] = dpp_sum(p17 ? -t5  : t5);
    es[4] = dpp_sum(p32 ? -t8  : t8);
    es[5] = dpp_sum(p16 ? -t4  : t4);
    es[6] = dpp_sum(p8  ? -t2  : t2);
    es[7] = dpp_sum(p4  ? -t1  : t1);
    es[8] = dpp_sum(p34 ? -t8  : t8);
    es[9] = dpp_sum(p17 ? -t4  : t4);

    // ---- head: lane owns output cols (2*lane, 2*lane+1); W3 rows direct (L1-hot) ----
    const float4* __restrict__ w3r = (const float4*)(W3 + (size_t)lane * 2 * NQ);
    float4 wA = w3r[0], wB = w3r[1], wC = w3r[2], wD = w3r[3], wE = w3r[4];
    float2 b3v = ((const float2*)b3)[lane];
    float dd0 = b3v.x;
    dd0 = fmaf(wA.x, es[0], dd0); dd0 = fmaf(wA.y, es[1], dd0);
    dd0 = fmaf(wA.z, es[2], dd0); dd0 = fmaf(wA.w, es[3], dd0);
    dd0 = fmaf(wB.x, es[4], dd0); dd0 = fmaf(wB.y, es[5], dd0);
    dd0 = fmaf(wB.z, es[6], dd0); dd0 = fmaf(wB.w, es[7], dd0);
    dd0 = fmaf(wC.x, es[8], dd0); dd0 = fmaf(wC.y, es[9], dd0);
    float dd1 = b3v.y;
    dd1 = fmaf(wC.z, es[0], dd1); dd1 = fmaf(wC.w, es[1], dd1);
    dd1 = fmaf(wD.x, es[2], dd1); dd1 = fmaf(wD.y, es[3], dd1);
    dd1 = fmaf(wD.z, es[4], dd1); dd1 = fmaf(wD.w, es[5], dd1);
    dd1 = fmaf(wE.x, es[6], dd1); dd1 = fmaf(wE.y, es[7], dd1);
    dd1 = fmaf(wE.z, es[8], dd1); dd1 = fmaf(wE.w, es[9], dd1);
    dd0 = fmaxf(dd0, 0.f);
    dd1 = fmaxf(dd1, 0.f);
    float2 w4v = ((const float2*)W4)[lane];
    float accv = fmaf(dd0, w4v.x, dd1 * w4v.y);
    accv = dpp_sum(accv);
    if (lane == 0) out[row] = accv + b4[0];
}

extern "C" void kernel_launch(void* const* d_in, const int* in_sizes, int n_in,
                              void* d_out, int out_size, void* d_ws, size_t ws_size,
                              hipStream_t stream) {
    const float* x  = (const float*)d_in[0];
    const float* W1 = (const float*)d_in[1];
    const float* b1 = (const float*)d_in[2];
    const float* W2 = (const float*)d_in[3];
    const float* b2 = (const float*)d_in[4];
    const float* qw = (const float*)d_in[5];
    const float* W3 = (const float*)d_in[6];
    const float* b3 = (const float*)d_in[7];
    const float* W4 = (const float*)d_in[8];
    const float* b4 = (const float*)d_in[9];
    float* gtab = (float*)d_ws;                    // 40*48 = 1920 floats
    float* w1q  = (float*)d_ws + 2048;             // 32768 floats (pair-packed)
    float* dtab = (float*)d_ws + 2048 + 32768;     // 6144 floats (3 merged RZ diagonals)
    float* out  = (float*)d_out;

    prep_kernel<<<(128 * 64 + 255) / 256, 256, 0, stream>>>(qw, W1, gtab, w1q, dtab);
    fused_kernel<<<BATCH / 4, 256, 0, stream>>>(x, w1q, b1, W2, b2, gtab, dtab, W3, b3, W4, b4, out);
}